// Round 5
// baseline (83616.498 us; speedup 1.0000x reference)
//
#include <hip/hip_runtime.h>
#include <math.h>

#define B_    512
#define T_    512
#define H_    256
#define DIN_  64
#define OL_   8
#define DOUT_ 64

typedef unsigned short u16;
typedef unsigned int u32;
typedef __attribute__((ext_vector_type(8))) short short8;   // 8 bf16 (MFMA A/B frag)
typedef __attribute__((ext_vector_type(4))) float f32x4;    // MFMA C/D frag (16x16)

static __device__ __forceinline__ float sigm(float x){ return 1.0f/(1.0f + expf(-x)); }
static __device__ __forceinline__ float bf2f(u16 h){
  u32 u = ((u32)h) << 16; float f; __builtin_memcpy(&f, &u, 4); return f;
}
static __device__ __forceinline__ u16 f2bf(float f){        // RNE
  u32 u; __builtin_memcpy(&u, &f, 4);
  u = (u + 0x7fffu + ((u >> 16) & 1u)) >> 16;
  return (u16)u;
}
static __device__ __forceinline__ u32 packhl(float f){      // hi<<16 | lo
  u16 h = f2bf(f);
  u16 lo = f2bf(f - bf2f(h));
  return ((u32)h << 16) | (u32)lo;
}

// ---------------------------------------------------------------------------
// Weight preps
// ---------------------------------------------------------------------------
// WpT[c][d] = sum_e in_W[d][e] * enc_Wih[c][e]   (fold input proj into gates)
__global__ void k_wpt(const float* __restrict__ inW, const float* __restrict__ Wih,
                      float* __restrict__ WpT)
{
  int gid = blockIdx.x * 256 + threadIdx.x;   // 65536
  int c = gid >> 6, d = gid & 63;
  const float* wr = Wih + c * H_;
  const float* ir = inW + d * H_;
  float acc = 0.f;
  #pragma unroll 4
  for (int e = 0; e < H_; e += 4) {
    float4 av = *(const float4*)(ir + e);
    float4 bv = *(const float4*)(wr + e);
    acc += av.x*bv.x + av.y*bv.y + av.z*bv.z + av.w*bv.w;
  }
  WpT[c*64 + d] = acc;
}

// bp[c] = in_b . Wih[c,:] + bih[c] + bhh[c]
__global__ void k_bp(const float* __restrict__ inb, const float* __restrict__ Wih,
                     const float* __restrict__ bih, const float* __restrict__ bhh,
                     float* __restrict__ bp)
{
  int c = blockIdx.x * 256 + threadIdx.x;   // 1024
  const float* wr = Wih + c * H_;
  float acc = bih[c] + bhh[c];
  for (int e = 0; e < H_; ++e) acc += inb[e] * wr[e];
  bp[c] = acc;
}

// dWt[k][j], j<768 covering dec gates i,g,o (f dead: c0=0)
__global__ void k_dwt(const float* __restrict__ dWih, float* __restrict__ dWt)
{
  int gid = blockIdx.x * 256 + threadIdx.x;   // 393216
  int j = gid >> 9, k = gid & 511;
  int row = (j < 256) ? j : (j + 256);
  dWt[k*768 + j] = dWih[row*512 + k];
}

// All 15 MLP weights W[k][n] -> fragment-linear bf16 hi/lo (one launch).
// FL[arr][s][ctg][lane][j] : k = s*32 + (lane>>4)*8 + j, n = ctg*16 + (lane&15)
__global__ void k_wall(const float* __restrict__ wWs, const float* __restrict__ wWl,
                       const float* __restrict__ uWs, const float* __restrict__ uWl,
                       const float* __restrict__ vWs, u16* __restrict__ outb)
{
  int lyr = blockIdx.y;
  const float* W = (lyr < 3)  ? wWs + lyr*65536
                 : (lyr == 3) ? wWl
                 : (lyr < 7)  ? uWs + (lyr-4)*65536
                 : (lyr == 7) ? uWl
                 :              vWs + (lyr-8)*65536;
  u16* out = outb + (size_t)lyr*131072;
  int gid = blockIdx.x * 256 + threadIdx.x;   // 65536
  int k = gid & 255, n = gid >> 8;
  float v = W[k*256 + n];
  int s = k >> 5, j = k & 7;
  int lane = (((k >> 3) & 3) << 4) | (n & 15);
  int fl = ((s*16) + (n >> 4))*512 + lane*8 + j;
  u16 h = f2bf(v);
  out[fl] = h;
  out[65536 + fl] = f2bf(v - bf2f(h));
}

// Whh (1024x256) -> wave/gate fragment-linear for 16-wave encoder:
// ctg = wave*4 + gate ; frag col (l&15) = unit wave*16+(l&15)
__global__ void k_whhfl(const float* __restrict__ Whh, u16* __restrict__ out)
{
  int gid = blockIdx.x * 256 + threadIdx.x;   // 262144
  int j = gid & 7, l = (gid >> 3) & 63, ctg = (gid >> 9) & 63, s = gid >> 15;
  int k = s*32 + (l >> 4)*8 + j;
  int wv = ctg >> 2, g = ctg & 3;
  int row = g*256 + wv*16 + (l & 15);
  float v = Whh[row*256 + k];
  int fl = (s*64 + ctg)*512 + l*8 + j;
  u16 h = f2bf(v);
  out[fl] = h;
  out[262144 + fl] = f2bf(v - bf2f(h));
}

// WpT (1024x64) -> same wave/gate fragment-linear (K=64)
__global__ void k_wpfl(const float* __restrict__ WpT, u16* __restrict__ out)
{
  int gid = blockIdx.x * 256 + threadIdx.x;   // 65536
  int j = gid & 7, l = (gid >> 3) & 63, ctg = (gid >> 9) & 63, s = gid >> 15;
  int k = s*32 + (l >> 4)*8 + j;              // < 64
  int wv = ctg >> 2, g = ctg & 3;
  int row = g*256 + wv*16 + (l & 15);
  float v = WpT[row*64 + k];
  int fl = (s*64 + ctg)*512 + l*8 + j;
  u16 h = f2bf(v);
  out[fl] = h;
  out[65536 + fl] = f2bf(v - bf2f(h));
}

// ---------------------------------------------------------------------------
// Encoder: one 1024-thr block owns 16 batch rows x ALL 1024 gate cols.
// 16 waves, wave w = units w*16..+15, gates i/f/g/o as ct 0..3 -> epilogue is
// lane-local. Weights in registers; h in LDS (XOR-swizzled); per-step sync =
// __syncthreads only. grid = CB/16 independent blocks. No fences, no global h.
// ---------------------------------------------------------------------------
__global__ __launch_bounds__(1024) void k_enc_blk(
    const float* __restrict__ x, const u16* __restrict__ whhFL,
    const u16* __restrict__ wpFL, const float* __restrict__ bp,
    float* __restrict__ enc)
{
  __shared__ u32 hl[4096];   // [16 rows][256 units] u32 hi|lo, chunk-XOR-swizzled
  const int tid = threadIdx.x, l = tid & 63, w = tid >> 6;
  const int lr = l & 15, lk = l >> 4;
  const int b0 = blockIdx.x * 16;

  // ---- persistent weight fragments
  short8 whH[8][4], whL[8][4], wpH[2][4], wpL[2][4];
  #pragma unroll
  for (int s = 0; s < 8; ++s)
    #pragma unroll
    for (int g = 0; g < 4; ++g) {
      int ctg = w*4 + g;
      whH[s][g] = *(const short8*)(whhFL + ((size_t)(s*64 + ctg))*512 + l*8);
      whL[s][g] = *(const short8*)(whhFL + 262144 + ((size_t)(s*64 + ctg))*512 + l*8);
    }
  #pragma unroll
  for (int s = 0; s < 2; ++s)
    #pragma unroll
    for (int g = 0; g < 4; ++g) {
      int ctg = w*4 + g;
      wpH[s][g] = *(const short8*)(wpFL + ((size_t)(s*64 + ctg))*512 + l*8);
      wpL[s][g] = *(const short8*)(wpFL + 65536 + ((size_t)(s*64 + ctg))*512 + l*8);
    }
  float bi[4];
  #pragma unroll
  for (int g = 0; g < 4; ++g) bi[g] = bp[g*256 + w*16 + lr];

  for (int i = tid; i < 4096; i += 1024) hl[i] = 0;
  f32x4 cs = (f32x4){0.f,0.f,0.f,0.f};
  __syncthreads();

  const float* xrow = x + ((size_t)(b0 + lr)*T_)*DIN_ + lk*8;

  for (int t = 0; t < T_; ++t) {
    // x(t) early (latency hides under h MFMAs)
    float4 xv0 = *(const float4*)(xrow);
    float4 xv1 = *(const float4*)(xrow + 4);
    float4 xv2 = *(const float4*)(xrow + 32);
    float4 xv3 = *(const float4*)(xrow + 36);
    xrow += DIN_;

    f32x4 acc[4];
    #pragma unroll
    for (int g = 0; g < 4; ++g) acc[g] = (f32x4){0.f,0.f,0.f,0.f};

    // ---- h @ Whh' (K=256); A frag: row=lr, k=s*32+lk*8+j
    #pragma unroll
    for (int s = 0; s < 8; ++s) {
      int cc = s*8 + lk*2;
      const u32* hb = hl + lr*256;
      uint4 d0 = *(const uint4*)(hb + (((cc    ) ^ lr) << 2));
      uint4 d1 = *(const uint4*)(hb + (((cc + 1) ^ lr) << 2));
      u32 q[8] = {d0.x,d0.y,d0.z,d0.w,d1.x,d1.y,d1.z,d1.w};
      short8 ah, al;
      #pragma unroll
      for (int j = 0; j < 8; ++j) { ah[j] = (short)(q[j] >> 16); al[j] = (short)(q[j] & 0xffff); }
      #pragma unroll
      for (int g = 0; g < 4; ++g) {
        acc[g] = __builtin_amdgcn_mfma_f32_16x16x32_bf16(ah, whH[s][g], acc[g], 0,0,0);
        acc[g] = __builtin_amdgcn_mfma_f32_16x16x32_bf16(al, whH[s][g], acc[g], 0,0,0);
        acc[g] = __builtin_amdgcn_mfma_f32_16x16x32_bf16(ah, whL[s][g], acc[g], 0,0,0);
      }
    }
    // ---- x @ Wp' (K=64), split on the fly
    #pragma unroll
    for (int s = 0; s < 2; ++s) {
      float vv[8];
      if (s == 0) { vv[0]=xv0.x;vv[1]=xv0.y;vv[2]=xv0.z;vv[3]=xv0.w;vv[4]=xv1.x;vv[5]=xv1.y;vv[6]=xv1.z;vv[7]=xv1.w; }
      else        { vv[0]=xv2.x;vv[1]=xv2.y;vv[2]=xv2.z;vv[3]=xv2.w;vv[4]=xv3.x;vv[5]=xv3.y;vv[6]=xv3.z;vv[7]=xv3.w; }
      short8 ah, al;
      #pragma unroll
      for (int j = 0; j < 8; ++j) {
        u16 h = f2bf(vv[j]);
        ah[j] = (short)h;
        al[j] = (short)f2bf(vv[j] - bf2f(h));
      }
      #pragma unroll
      for (int g = 0; g < 4; ++g) {
        acc[g] = __builtin_amdgcn_mfma_f32_16x16x32_bf16(ah, wpH[s][g], acc[g], 0,0,0);
        acc[g] = __builtin_amdgcn_mfma_f32_16x16x32_bf16(al, wpH[s][g], acc[g], 0,0,0);
        acc[g] = __builtin_amdgcn_mfma_f32_16x16x32_bf16(ah, wpL[s][g], acc[g], 0,0,0);
      }
    }

    __syncthreads();   // all h(t) reads complete before overwrite

    // ---- lane-local epilogue: rows lk*4+r, unit w*16+lr
    #pragma unroll
    for (int r = 0; r < 4; ++r) {
      float gi = acc[0][r] + bi[0];
      float gf = acc[1][r] + bi[1];
      float gg = acc[2][r] + bi[2];
      float go = acc[3][r] + bi[3];
      float cn = sigm(gf)*cs[r] + sigm(gi)*tanhf(gg);
      float hn = sigm(go)*tanhf(cn);
      cs[r] = cn;
      int row = lk*4 + r, unit = w*16 + lr;
      int cc2 = unit >> 2;
      hl[row*256 + ((cc2 ^ row) << 2) + (unit & 3)] = packhl(hn);
      enc[((size_t)(b0 + row)*T_ + t)*256 + unit] = hn;
    }
    __syncthreads();   // h(t+1) visible
  }
}

// ---------------------------------------------------------------------------
// Fused multi-layer MLP. 128-row act tile in LDS across all layers.
// Waves: 2 row-groups x 4 col-groups (B L2-traffic dup 2x instead of 4x).
// IN: 0 = A0 fp32; 1 = tanh(A0 + us[row>>9]).  FIN: 0 = fp32 C; 1 = dot vWl.
// ---------------------------------------------------------------------------
template<int IN, int FIN>
__global__ __launch_bounds__(512,1) void k_mlp(
    const float* __restrict__ A0, const float* __restrict__ usp,
    const u16* __restrict__ wFL, const float* __restrict__ bs,
    const float* __restrict__ bl, float* __restrict__ Cout,
    float* __restrict__ eout, const float* __restrict__ vWl,
    const float* __restrict__ vbl, int L, int nbs)
{
  extern __shared__ u32 act[];   // [128][256] u32, chunk-swizzled (key row&7)
  const int tid = threadIdx.x, l = tid & 63, w = tid >> 6;
  const int rg = w >> 2, cg = w & 3;
  const int lr = l & 15, lk = l >> 4;
  const int wrow = rg*64;
  const long m0 = (long)blockIdx.x * 128;

  for (int i = tid; i < 8192; i += 512) {        // 128 rows x 64 chunks
    int row = i >> 6, c16 = i & 63;
    long m = m0 + row;
    float4 v = *(const float4*)(A0 + m*256 + c16*4);
    if (IN == 1) {
      const float* ub = usp + (size_t)(m >> 9)*256;
      float4 u4 = *(const float4*)(ub + c16*4);
      v.x = tanhf(v.x + u4.x); v.y = tanhf(v.y + u4.y);
      v.z = tanhf(v.z + u4.z); v.w = tanhf(v.w + u4.w);
    }
    u32* dst = act + row*256 + (c16 ^ (row & 7))*4;
    ((uint4*)dst)[0] = (uint4){packhl(v.x), packhl(v.y), packhl(v.z), packhl(v.w)};
  }

  f32x4 acc[4][4];
  for (int lyr = 0; lyr < L; ++lyr) {
    __syncthreads();
    const u16* wb = wFL + (size_t)lyr*131072;
    #pragma unroll
    for (int rt = 0; rt < 4; ++rt)
      #pragma unroll
      for (int ct = 0; ct < 4; ++ct) acc[rt][ct] = (f32x4){0.f,0.f,0.f,0.f};

    #pragma unroll
    for (int s = 0; s < 8; ++s) {
      // B frags first (global; hoistable across unrolled iterations)
      short8 bh[4], blo[4];
      #pragma unroll
      for (int ct = 0; ct < 4; ++ct) {
        const u16* bfp = wb + ((size_t)(s*16 + cg*4 + ct))*512 + l*8;
        bh[ct]  = *(const short8*)bfp;
        blo[ct] = *(const short8*)(bfp + 65536);
      }
      short8 ah[4], al[4];
      #pragma unroll
      for (int rt = 0; rt < 4; ++rt) {
        int row = wrow + rt*16 + lr;
        int cc = s*8 + lk*2;
        const u32* base = act + row*256;
        uint4 d0 = *(const uint4*)(base + (((cc    ) ^ (row & 7)) << 2));
        uint4 d1 = *(const uint4*)(base + (((cc + 1) ^ (row & 7)) << 2));
        u32 q[8] = {d0.x,d0.y,d0.z,d0.w,d1.x,d1.y,d1.z,d1.w};
        #pragma unroll
        for (int j = 0; j < 8; ++j) {
          ah[rt][j] = (short)(q[j] >> 16);
          al[rt][j] = (short)(q[j] & 0xffff);
        }
      }
      #pragma unroll
      for (int ct = 0; ct < 4; ++ct)
        #pragma unroll
        for (int rt = 0; rt < 4; ++rt) {
          acc[rt][ct] = __builtin_amdgcn_mfma_f32_16x16x32_bf16(ah[rt], bh[ct],  acc[rt][ct], 0,0,0);
          acc[rt][ct] = __builtin_amdgcn_mfma_f32_16x16x32_bf16(al[rt], bh[ct],  acc[rt][ct], 0,0,0);
          acc[rt][ct] = __builtin_amdgcn_mfma_f32_16x16x32_bf16(ah[rt], blo[ct], acc[rt][ct], 0,0,0);
        }
    }
    const float* bptr = (lyr < nbs) ? (bs + lyr*256) : bl;
    const bool dorelu = (lyr < L-1) || (FIN == 1);
    #pragma unroll
    for (int ct = 0; ct < 4; ++ct) {
      float bv = bptr[cg*64 + ct*16 + lr];
      #pragma unroll
      for (int rt = 0; rt < 4; ++rt)
        #pragma unroll
        for (int g = 0; g < 4; ++g) {
          float xv = acc[rt][ct][g] + bv;
          acc[rt][ct][g] = dorelu ? fmaxf(xv, 0.f) : xv;
        }
    }
    if (lyr == L-1) break;
    __syncthreads();
    #pragma unroll
    for (int ct = 0; ct < 4; ++ct) {
      int n = cg*64 + ct*16 + lr;
      #pragma unroll
      for (int rt = 0; rt < 4; ++rt)
        #pragma unroll
        for (int g = 0; g < 4; ++g) {
          int row = wrow + rt*16 + lk*4 + g;
          act[row*256 + (((n >> 2) ^ (row & 7)) << 2) + (n & 3)] = packhl(acc[rt][ct][g]);
        }
    }
  }

  if (FIN == 0) {
    #pragma unroll
    for (int ct = 0; ct < 4; ++ct) {
      int n = cg*64 + ct*16 + lr;
      #pragma unroll
      for (int rt = 0; rt < 4; ++rt)
        #pragma unroll
        for (int g = 0; g < 4; ++g) {
          long m = m0 + wrow + rt*16 + lk*4 + g;
          Cout[m*256 + n] = acc[rt][ct][g];
        }
    }
  } else {
    float part[4][4];
    #pragma unroll
    for (int rt = 0; rt < 4; ++rt)
      #pragma unroll
      for (int g = 0; g < 4; ++g) part[rt][g] = 0.f;
    #pragma unroll
    for (int ct = 0; ct < 4; ++ct) {
      float vw = vWl[cg*64 + ct*16 + lr];
      #pragma unroll
      for (int rt = 0; rt < 4; ++rt)
        #pragma unroll
        for (int g = 0; g < 4; ++g) part[rt][g] += acc[rt][ct][g] * vw;
    }
    #pragma unroll
    for (int o = 1; o < 16; o <<= 1)
      #pragma unroll
      for (int rt = 0; rt < 4; ++rt)
        #pragma unroll
        for (int g = 0; g < 4; ++g) part[rt][g] += __shfl_xor(part[rt][g], o, 64);
    __syncthreads();
    float* ep = (float*)act;                      // [4][128]
    if ((l & 15) == 0) {
      #pragma unroll
      for (int rt = 0; rt < 4; ++rt)
        #pragma unroll
        for (int g = 0; g < 4; ++g)
          ep[cg*128 + wrow + rt*16 + lk*4 + g] = part[rt][g];
    }
    __syncthreads();
    for (int r = tid; r < 128; r += 512)
      eout[m0 + r] = ep[r] + ep[128 + r] + ep[256 + r] + ep[384 + r] + vbl[0];
  }
}

// ---------------------------------------------------------------------------
// Fused softmax + context.
// ---------------------------------------------------------------------------
__global__ __launch_bounds__(256,2) void k_attn(const float* __restrict__ e,
    const float* __restrict__ enc, float* __restrict__ ct)
{
  __shared__ float as[512];
  __shared__ float red[8];
  const int b = blockIdx.x, tid = threadIdx.x;
  const int lane = tid & 63, w = tid >> 6;
  float v0 = e[b*512 + tid], v1 = e[b*512 + 256 + tid];
  float m = fmaxf(v0, v1);
  #pragma unroll
  for (int o = 32; o; o >>= 1) m = fmaxf(m, __shfl_xor(m, o, 64));
  if (!lane) red[w] = m;
  __syncthreads();
  m = fmaxf(fmaxf(red[0], red[1]), fmaxf(red[2], red[3]));
  float x0 = expf(v0 - m), x1 = expf(v1 - m);
  float sm = x0 + x1;
  #pragma unroll
  for (int o = 32; o; o >>= 1) sm += __shfl_xor(sm, o, 64);
  if (!lane) red[4 + w] = sm;
  __syncthreads();
  float inv = 1.f / (red[4] + red[5] + red[6] + red[7]);
  as[tid] = x0 * inv;
  as[256 + tid] = x1 * inv;
  __syncthreads();
  float acc = 0.f;
  const float* ep = enc + (size_t)b*(T_*H_) + tid;
  #pragma unroll 8
  for (int t = 0; t < 512; ++t) acc += as[t] * ep[t*H_];
  ct[b*H_ + tid] = acc;
}

__global__ __launch_bounds__(256,2) void k_dec_cell(
    const float* __restrict__ ct, float* __restrict__ s, const float* __restrict__ dWt,
    const float* __restrict__ bih, const float* __restrict__ bhh,
    float* __restrict__ dec, int step)
{
  __shared__ float xt[8][516];
  const int tid = threadIdx.x;
  const int b0 = blockIdx.x * 8;
  for (int f = tid; f < 8*128; f += 256) {
    int bb = f >> 7, k4 = f & 127;
    float4 v = (k4 < 64) ? *(const float4*)(ct + (b0+bb)*H_ + k4*4)
                         : *(const float4*)(s  + (b0+bb)*H_ + (k4-64)*4);
    *(float4*)(&xt[bb][k4*4]) = v;
  }
  __syncthreads();
  const int u = tid;
  float ai[8], ag[8], ao[8];
  #pragma unroll
  for (int bb = 0; bb < 8; ++bb) { ai[bb]=0.f; ag[bb]=0.f; ao[bb]=0.f; }
  #pragma unroll 2
  for (int k = 0; k < 512; ++k) {
    float wi = dWt[k*768 + u];
    float wg = dWt[k*768 + 256 + u];
    float wo = dWt[k*768 + 512 + u];
    #pragma unroll
    for (int bb = 0; bb < 8; ++bb) {
      float xv = xt[bb][k];
      ai[bb] += xv*wi; ag[bb] += xv*wg; ao[bb] += xv*wo;
    }
  }
  float bi = bih[u]       + bhh[u];
  float bg = bih[512 + u] + bhh[512 + u];
  float bo = bih[768 + u] + bhh[768 + u];
  #pragma unroll
  for (int bb = 0; bb < 8; ++bb) {
    int b = b0 + bb;
    float cn = sigm(ai[bb] + bi) * tanhf(ag[bb] + bg);
    float hn = sigm(ao[bb] + bo) * tanhf(cn);
    s[b*H_ + u] = hn;
    dec[((size_t)b*OL_ + step)*H_ + u] = hn;
  }
}

__global__ __launch_bounds__(256,2) void k_outproj(
    const float* __restrict__ dec, const float* __restrict__ oW,
    const float* __restrict__ ob, float* __restrict__ out)
{
  const int tid = threadIdx.x;
  const int m0 = blockIdx.x * 16;
  const int d = tid & 63, rr = tid >> 6;
  float bv = ob[d];
  for (int p = 0; p < 4; ++p) {
    int m = m0 + p*4 + rr;
    const float* ar = dec + (size_t)m*H_;
    float acc = bv;
    #pragma unroll 4
    for (int k = 0; k < H_; ++k) acc += ar[k] * oW[k*64 + d];
    out[(size_t)m*64 + d] = acc;
  }
}

// ---------------------------------------------------------------------------
extern "C" void kernel_launch(void* const* d_in, const int* in_sizes, int n_in,
                              void* d_out, int out_size, void* d_ws, size_t ws_size,
                              hipStream_t stream)
{
  (void)in_sizes; (void)n_in;
  const float* x    = (const float*)d_in[0];
  const float* inW  = (const float*)d_in[1];
  const float* inb  = (const float*)d_in[2];
  const float* eWih = (const float*)d_in[3];
  const float* eWhh = (const float*)d_in[4];
  const float* ebih = (const float*)d_in[5];
  const float* ebhh = (const float*)d_in[6];
  const float* dWih = (const float*)d_in[7];
  const float* dbih = (const float*)d_in[9];
  const float* dbhh = (const float*)d_in[10];
  const float* wWs  = (const float*)d_in[11];
  const float* wbs  = (const float*)d_in[12];
  const float* wWl  = (const float*)d_in[13];
  const float* wbl  = (const float*)d_in[14];
  const float* uWs  = (const float*)d_in[15];
  const float* ubs  = (const float*)d_in[16];
  const float* uWl  = (const float*)d_in[17];
  const float* ubl  = (const float*)d_in[18];
  const float* vWs  = (const float*)d_in[19];
  const float* vbs  = (const float*)d_in[20];
  const float* vWl  = (const float*)d_in[21];
  const float* vbl  = (const float*)d_in[22];
  const float* oW   = (const float*)d_in[23];
  const float* ob   = (const float*)d_in[24];
  float* out = (float*)d_out;

  hipFuncSetAttribute((const void*)k_mlp<0,0>, hipFuncAttributeMaxDynamicSharedMemorySize, 131072);
  hipFuncSetAttribute((const void*)k_mlp<1,1>, hipFuncAttributeMaxDynamicSharedMemorySize, 131072);

  const size_t avail = ws_size / 4;
  auto need = [](int cb) -> size_t {
    return 2ull*cb*T_*H_ + (size_t)cb*3328 + 1800000ull;
  };
  int CB = 512;
  while (CB > 128 && need(CB) > avail) CB >>= 1;
  if (need(CB) > avail) { hipMemsetAsync(d_out, 0, (size_t)out_size*4, stream); return; }

  float* wsf = (float*)d_ws;
  size_t o = 0;
  float* enc = wsf + o;  o += (size_t)CB*T_*H_;
  float* whs = wsf + o;  o += (size_t)CB*T_*H_;
  float* sbuf= wsf + o;  o += (size_t)CB*256;
  float* us  = wsf + o;  o += (size_t)CB*256;
  float* ctx = wsf + o;  o += (size_t)CB*256;
  float* dec = wsf + o;  o += (size_t)CB*2048;
  float* e   = wsf + o;  o += (size_t)CB*512;
  float* WpT = wsf + o;  o += 65536;
  float* bp  = wsf + o;  o += 1024;
  float* dWt = wsf + o;  o += 393216;
  u16* whhFL = (u16*)(wsf + o);  o += 262144;
  u16* wpFL  = (u16*)(wsf + o);  o += 65536;
  u16* mlpFL = (u16*)(wsf + o);

  // ---- weight preps (chunk-invariant)
  k_wpt<<<256, 256, 0, stream>>>(inW, eWih, WpT);
  k_bp <<<4,   256, 0, stream>>>(inb, eWih, ebih, ebhh, bp);
  k_dwt<<<1536,256, 0, stream>>>(dWih, dWt);
  k_whhfl<<<1024,256,0,stream>>>(eWhh, whhFL);
  k_wpfl <<<256, 256,0,stream>>>(WpT, wpFL);
  k_wall <<<dim3(256,15), 256, 0, stream>>>(wWs, wWl, uWs, uWl, vWs, mlpFL);

  const int gBig = CB * 4;
  const int gU   = CB / 128;

  for (int c0 = 0; c0 < B_; c0 += CB) {
    const float* xc = x + (size_t)c0*T_*DIN_;
    float* outc = out + (size_t)c0*OL_*DOUT_;

    hipMemsetAsync(sbuf, 0, (size_t)CB*256*4, stream);   // decode s0 = 0

    // ---- encoder: independent 16-row blocks, all T steps internal
    k_enc_blk<<<CB/16, 1024, 0, stream>>>(xc, whhFL, wpFL, bp, enc);

    // ---- whs = w_mlp(enc)
    k_mlp<0,0><<<gBig, 512, 131072, stream>>>(enc, nullptr, mlpFL, wbs, wbl,
                                              whs, nullptr, nullptr, nullptr, 4, 3);

    // ---- decode loop
    for (int step = 0; step < OL_; ++step) {
      k_mlp<0,0><<<gU, 512, 131072, stream>>>(sbuf, nullptr, mlpFL + 4ull*131072, ubs, ubl,
                                              us, nullptr, nullptr, nullptr, 4, 3);
      k_mlp<1,1><<<gBig, 512, 131072, stream>>>(whs, us, mlpFL + 8ull*131072, vbs, nullptr,
                                                nullptr, e, vWl, vbl, 7, 7);
      k_attn<<<CB, 256, 0, stream>>>(e, enc, ctx);
      k_dec_cell<<<CB/8, 256, 0, stream>>>(ctx, sbuf, dWt, dbih, dbhh, dec, step);
    }
    k_outproj<<<CB/2, 256, 0, stream>>>(dec, oW, ob, outc);
  }
}

// Round 6
// 27305.942 us; speedup vs baseline: 3.0622x; 3.0622x over previous
//
#include <hip/hip_runtime.h>
#include <math.h>

#define B_    512
#define T_    512
#define H_    256
#define DIN_  64
#define OL_   8
#define DOUT_ 64

typedef unsigned short u16;
typedef unsigned int u32;
typedef unsigned long long ull;
typedef __attribute__((ext_vector_type(8))) short short8;   // 8 bf16 (MFMA A/B frag)
typedef __attribute__((ext_vector_type(4))) float f32x4;    // MFMA C/D frag (16x16)

static __device__ __forceinline__ float sigm(float x){ return 1.0f/(1.0f + expf(-x)); }
static __device__ __forceinline__ float bf2f(u16 h){
  u32 u = ((u32)h) << 16; float f; __builtin_memcpy(&f, &u, 4); return f;
}
static __device__ __forceinline__ u16 f2bf(float f){        // RNE
  u32 u; __builtin_memcpy(&u, &f, 4);
  u = (u + 0x7fffu + ((u >> 16) & 1u)) >> 16;
  return (u16)u;
}
static __device__ __forceinline__ u32 packhl(float f){      // hi<<16 | lo
  u16 h = f2bf(f);
  u16 lo = f2bf(f - bf2f(h));
  return ((u32)h << 16) | (u32)lo;
}
static __device__ __forceinline__ float unpackhl(u32 w){
  return bf2f((u16)(w >> 16)) + bf2f((u16)(w & 0xffff));
}

// ---------------------------------------------------------------------------
// Weight preps
// ---------------------------------------------------------------------------
// WpT[c][d] = sum_e in_W[d][e] * enc_Wih[c][e]   (fold input proj into gates)
__global__ void k_wpt(const float* __restrict__ inW, const float* __restrict__ Wih,
                      float* __restrict__ WpT)
{
  int gid = blockIdx.x * 256 + threadIdx.x;   // 65536
  int c = gid >> 6, d = gid & 63;
  const float* wr = Wih + c * H_;
  const float* ir = inW + d * H_;
  float acc = 0.f;
  #pragma unroll 4
  for (int e = 0; e < H_; e += 4) {
    float4 av = *(const float4*)(ir + e);
    float4 bv = *(const float4*)(wr + e);
    acc += av.x*bv.x + av.y*bv.y + av.z*bv.z + av.w*bv.w;
  }
  WpT[c*64 + d] = acc;
}

// bp[c] = in_b . Wih[c,:] + bih[c] + bhh[c]
__global__ void k_bp(const float* __restrict__ inb, const float* __restrict__ Wih,
                     const float* __restrict__ bih, const float* __restrict__ bhh,
                     float* __restrict__ bp)
{
  int c = blockIdx.x * 256 + threadIdx.x;   // 1024
  const float* wr = Wih + c * H_;
  float acc = bih[c] + bhh[c];
  for (int e = 0; e < H_; ++e) acc += inb[e] * wr[e];
  bp[c] = acc;
}

// dWt[k][j], j<768 covering dec gates i,g,o (f dead: c0=0)
__global__ void k_dwt(const float* __restrict__ dWih, float* __restrict__ dWt)
{
  int gid = blockIdx.x * 256 + threadIdx.x;   // 393216
  int j = gid >> 9, k = gid & 511;
  int row = (j < 256) ? j : (j + 256);
  dWt[k*768 + j] = dWih[row*512 + k];
}

// All 15 MLP weights W[k][n] -> fragment-linear bf16 hi/lo (one launch).
__global__ void k_wall(const float* __restrict__ wWs, const float* __restrict__ wWl,
                       const float* __restrict__ uWs, const float* __restrict__ uWl,
                       const float* __restrict__ vWs, u16* __restrict__ outb)
{
  int lyr = blockIdx.y;
  const float* W = (lyr < 3)  ? wWs + lyr*65536
                 : (lyr == 3) ? wWl
                 : (lyr < 7)  ? uWs + (lyr-4)*65536
                 : (lyr == 7) ? uWl
                 :              vWs + (lyr-8)*65536;
  u16* out = outb + (size_t)lyr*131072;
  int gid = blockIdx.x * 256 + threadIdx.x;   // 65536
  int k = gid & 255, n = gid >> 8;
  float v = W[k*256 + n];
  int s = k >> 5, j = k & 7;
  int lane = (((k >> 3) & 3) << 4) | (n & 15);
  int fl = ((s*16) + (n >> 4))*512 + lane*8 + j;
  u16 h = f2bf(v);
  out[fl] = h;
  out[65536 + fl] = f2bf(v - bf2f(h));
}

// Whh (1024x256) -> unit-group/gate fragment-linear: ctg = u16grp*4 + gate,
// frag col (l&15) = unit u16grp*16 + (l&15)
__global__ void k_whhfl(const float* __restrict__ Whh, u16* __restrict__ out)
{
  int gid = blockIdx.x * 256 + threadIdx.x;   // 262144
  int j = gid & 7, l = (gid >> 3) & 63, ctg = (gid >> 9) & 63, s = gid >> 15;
  int k = s*32 + (l >> 4)*8 + j;
  int wv = ctg >> 2, g = ctg & 3;
  int row = g*256 + wv*16 + (l & 15);
  float v = Whh[row*256 + k];
  int fl = (s*64 + ctg)*512 + l*8 + j;
  u16 h = f2bf(v);
  out[fl] = h;
  out[262144 + fl] = f2bf(v - bf2f(h));
}

// WpT (1024x64) -> same layout (K=64)
__global__ void k_wpfl(const float* __restrict__ WpT, u16* __restrict__ out)
{
  int gid = blockIdx.x * 256 + threadIdx.x;   // 65536
  int j = gid & 7, l = (gid >> 3) & 63, ctg = (gid >> 9) & 63, s = gid >> 15;
  int k = s*32 + (l >> 4)*8 + j;              // < 64
  int wv = ctg >> 2, g = ctg & 3;
  int row = g*256 + wv*16 + (l & 15);
  float v = WpT[row*64 + k];
  int fl = (s*64 + ctg)*512 + l*8 + j;
  u16 h = f2bf(v);
  out[fl] = h;
  out[65536 + fl] = f2bf(v - bf2f(h));
}

// ---------------------------------------------------------------------------
// Clustered persistent encoder. Cluster = 8 blocks (grid.y) x 16 rows (grid.x).
// Block (rg,bg): rows rg*16..+15, units bg*32..+31, all 4 gates.
// 4 waves x 256 thr, launch_bounds(256,1) -> 512 VGPR cap: weights resident
// (~160 VGPR/wave), NO spill. h exchanged as packhl u32 through the coherence
// point (relaxed agent atomics; no cache-flush fences). henc slot t = h(t-1);
// slot 0 zeroed; step t reads slot t, writes slot t+1 -> no overwrite race.
// Per-cluster barrier: syncthreads (drains stores) + tid0 fetch_add/spin.
// ---------------------------------------------------------------------------
__global__ __launch_bounds__(256,1) void k_enc(
    const float* __restrict__ x, const u16* __restrict__ whhFL,
    const u16* __restrict__ wpFL, const float* __restrict__ bp,
    u32* __restrict__ henc, unsigned* __restrict__ cnt, int CB)
{
  __shared__ float G[16][32][4];   // [row][unit_local][gate], 8 KB
  const int tid = threadIdx.x, l = tid & 63, wv = tid >> 6;
  const int lr = l & 15, lk = l >> 4;
  const int rg = blockIdx.x, bg = blockIdx.y;
  const int ug2 = wv >> 1;                 // unit-16 half within block
  const int g0 = (wv & 1) * 2;             // this wave's gate pair
  const int u16g = bg*2 + ug2;             // global unit-16 group

  // ---- resident weight fragments (no spill: ~160 VGPR)
  short8 whH[8][2], whL[8][2], wpH[2][2], wpL[2][2];
  #pragma unroll
  for (int s = 0; s < 8; ++s)
    #pragma unroll
    for (int c = 0; c < 2; ++c) {
      int ctg = u16g*4 + g0 + c;
      whH[s][c] = *(const short8*)(whhFL + ((size_t)(s*64 + ctg))*512 + l*8);
      whL[s][c] = *(const short8*)(whhFL + 262144 + ((size_t)(s*64 + ctg))*512 + l*8);
    }
  #pragma unroll
  for (int s = 0; s < 2; ++s)
    #pragma unroll
    for (int c = 0; c < 2; ++c) {
      int ctg = u16g*4 + g0 + c;
      wpH[s][c] = *(const short8*)(wpFL + ((size_t)(s*64 + ctg))*512 + l*8);
      wpL[s][c] = *(const short8*)(wpFL + 65536 + ((size_t)(s*64 + ctg))*512 + l*8);
    }
  // epilogue: thread handles (row = tid>>5 + 8p, unit_local = tid&31)
  const int ul = tid & 31, er0 = tid >> 5;
  float bb[4];
  #pragma unroll
  for (int g = 0; g < 4; ++g) bb[g] = bp[g*256 + bg*32 + ul];
  float cs[2] = {0.f, 0.f};

  const size_t hstride = (size_t)CB * 256;
  const float* xrow = x + ((size_t)(rg*16 + lr)*T_)*DIN_ + lk*8;
  unsigned* mycnt = cnt + rg;

  for (int t = 0; t < T_; ++t) {
    // ---- h(t-1) A-frags from coherence point (slot t)
    const ull* hb = (const ull*)(henc + (size_t)t*hstride + (size_t)(rg*16 + lr)*256);
    ull hq[8][4];
    #pragma unroll
    for (int s = 0; s < 8; ++s)
      #pragma unroll
      for (int q = 0; q < 4; ++q)
        hq[s][q] = __hip_atomic_load(hb + s*16 + lk*4 + q,
                                     __ATOMIC_RELAXED, __HIP_MEMORY_SCOPE_AGENT);
    // x(t)
    float4 xv0 = *(const float4*)(xrow);
    float4 xv1 = *(const float4*)(xrow + 4);
    float4 xv2 = *(const float4*)(xrow + 32);
    float4 xv3 = *(const float4*)(xrow + 36);
    xrow += DIN_;

    f32x4 acc[2];
    acc[0] = (f32x4){0.f,0.f,0.f,0.f};
    acc[1] = (f32x4){0.f,0.f,0.f,0.f};

    #pragma unroll
    for (int s = 0; s < 8; ++s) {
      short8 ah, al;
      #pragma unroll
      for (int q = 0; q < 4; ++q) {
        u32 w0 = (u32)hq[s][q], w1 = (u32)(hq[s][q] >> 32);
        ah[q*2]   = (short)(w0 >> 16); al[q*2]   = (short)(w0 & 0xffff);
        ah[q*2+1] = (short)(w1 >> 16); al[q*2+1] = (short)(w1 & 0xffff);
      }
      #pragma unroll
      for (int c = 0; c < 2; ++c) {
        acc[c] = __builtin_amdgcn_mfma_f32_16x16x32_bf16(ah, whH[s][c], acc[c], 0,0,0);
        acc[c] = __builtin_amdgcn_mfma_f32_16x16x32_bf16(al, whH[s][c], acc[c], 0,0,0);
        acc[c] = __builtin_amdgcn_mfma_f32_16x16x32_bf16(ah, whL[s][c], acc[c], 0,0,0);
      }
    }
    #pragma unroll
    for (int s = 0; s < 2; ++s) {
      float vv[8];
      if (s == 0) { vv[0]=xv0.x;vv[1]=xv0.y;vv[2]=xv0.z;vv[3]=xv0.w;vv[4]=xv1.x;vv[5]=xv1.y;vv[6]=xv1.z;vv[7]=xv1.w; }
      else        { vv[0]=xv2.x;vv[1]=xv2.y;vv[2]=xv2.z;vv[3]=xv2.w;vv[4]=xv3.x;vv[5]=xv3.y;vv[6]=xv3.z;vv[7]=xv3.w; }
      short8 ah, al;
      #pragma unroll
      for (int j = 0; j < 8; ++j) {
        u16 h = f2bf(vv[j]);
        ah[j] = (short)h;
        al[j] = (short)f2bf(vv[j] - bf2f(h));
      }
      #pragma unroll
      for (int c = 0; c < 2; ++c) {
        acc[c] = __builtin_amdgcn_mfma_f32_16x16x32_bf16(ah, wpH[s][c], acc[c], 0,0,0);
        acc[c] = __builtin_amdgcn_mfma_f32_16x16x32_bf16(al, wpH[s][c], acc[c], 0,0,0);
        acc[c] = __builtin_amdgcn_mfma_f32_16x16x32_bf16(ah, wpL[s][c], acc[c], 0,0,0);
      }
    }

    // ---- gate exchange (C layout: col=lr -> unit u16g*16+lr, row=lk*4+j)
    #pragma unroll
    for (int c = 0; c < 2; ++c)
      #pragma unroll
      for (int j = 0; j < 4; ++j)
        G[lk*4 + j][ug2*16 + lr][g0 + c] = acc[c][j];
    __syncthreads();

    // ---- epilogue: 2 (row,unit) pairs per thread; c in regs; h -> IC
    #pragma unroll
    for (int p = 0; p < 2; ++p) {
      int row = er0 + p*8;
      float4 gq = *(const float4*)&G[row][ul][0];
      float gi = gq.x + bb[0], gf = gq.y + bb[1];
      float gg = gq.z + bb[2], go = gq.w + bb[3];
      float cn = sigm(gf)*cs[p] + sigm(gi)*tanhf(gg);
      float hn = sigm(go)*tanhf(cn);
      cs[p] = cn;
      __hip_atomic_store(henc + (size_t)(t+1)*hstride + (size_t)(rg*16 + row)*256 + bg*32 + ul,
                         packhl(hn), __ATOMIC_RELAXED, __HIP_MEMORY_SCOPE_AGENT);
    }
    __syncthreads();                 // drains all waves' h-stores (vmcnt0 @ barrier)
    if (t < T_ - 1) {
      if (tid == 0) {
        __hip_atomic_fetch_add(mycnt, 1u, __ATOMIC_ACQ_REL, __HIP_MEMORY_SCOPE_AGENT);
        while (__hip_atomic_load(mycnt, __ATOMIC_ACQUIRE, __HIP_MEMORY_SCOPE_AGENT)
               < 8u*(unsigned)(t+1))
          __builtin_amdgcn_s_sleep(2);
      }
      __syncthreads();
    }
  }
}

// ---------------------------------------------------------------------------
// Fused multi-layer MLP. 128-row act tile in LDS (u32 hi|lo, chunk-swizzled),
// 8 waves = 2 row-groups x 4 col-groups. B explicitly double-buffered across
// the unrolled slab loop (prefetch s+1 under MFMA s).
// IN: 0 = A0 fp32; 1 = tanh(A0 + us[m & cbm1]); 2 = A0 is packhl u32 (copy).
// FIN: 0 = fp32 C; 1 = dot with vWl -> e.
// ---------------------------------------------------------------------------
template<int IN, int FIN>
__global__ __launch_bounds__(512,1) void k_mlp(
    const float* __restrict__ A0, const float* __restrict__ usp,
    const u16* __restrict__ wFL, const float* __restrict__ bs,
    const float* __restrict__ bl, float* __restrict__ Cout,
    float* __restrict__ eout, const float* __restrict__ vWl,
    const float* __restrict__ vbl, int L, int nbs, int cbm1)
{
  extern __shared__ u32 act[];   // [128][256] u32, chunk-swizzled (key row&7)
  const int tid = threadIdx.x, l = tid & 63, w = tid >> 6;
  const int rg = w >> 2, cg = w & 3;
  const int lr = l & 15, lk = l >> 4;
  const int wrow = rg*64;
  const long m0 = (long)blockIdx.x * 128;

  for (int i = tid; i < 8192; i += 512) {        // 128 rows x 64 chunks
    int row = i >> 6, c16 = i & 63;
    long m = m0 + row;
    uint4 pk;
    if (IN == 2) {
      pk = *(const uint4*)((const u32*)A0 + m*256 + c16*4);
    } else {
      float4 v = *(const float4*)(A0 + m*256 + c16*4);
      if (IN == 1) {
        const float* ub = usp + (size_t)(m & cbm1)*256;
        float4 u4 = *(const float4*)(ub + c16*4);
        v.x = tanhf(v.x + u4.x); v.y = tanhf(v.y + u4.y);
        v.z = tanhf(v.z + u4.z); v.w = tanhf(v.w + u4.w);
      }
      pk = (uint4){packhl(v.x), packhl(v.y), packhl(v.z), packhl(v.w)};
    }
    *((uint4*)(act + row*256 + (c16 ^ (row & 7))*4)) = pk;
  }

  f32x4 acc[4][4];
  for (int lyr = 0; lyr < L; ++lyr) {
    __syncthreads();
    const u16* wb = wFL + (size_t)lyr*131072;
    #pragma unroll
    for (int rt = 0; rt < 4; ++rt)
      #pragma unroll
      for (int ct = 0; ct < 4; ++ct) acc[rt][ct] = (f32x4){0.f,0.f,0.f,0.f};

    short8 bh[2][4], blo[2][4];
    #pragma unroll
    for (int ct = 0; ct < 4; ++ct) {
      const u16* bfp = wb + ((size_t)(cg*4 + ct))*512 + l*8;
      bh[0][ct]  = *(const short8*)bfp;
      blo[0][ct] = *(const short8*)(bfp + 65536);
    }
    #pragma unroll
    for (int s = 0; s < 8; ++s) {
      const int pb = s & 1, nb = pb ^ 1;
      if (s < 7) {
        #pragma unroll
        for (int ct = 0; ct < 4; ++ct) {
          const u16* bfp = wb + ((size_t)((s+1)*16 + cg*4 + ct))*512 + l*8;
          bh[nb][ct]  = *(const short8*)bfp;
          blo[nb][ct] = *(const short8*)(bfp + 65536);
        }
      }
      short8 ah[4], al[4];
      #pragma unroll
      for (int rt = 0; rt < 4; ++rt) {
        int row = wrow + rt*16 + lr;
        int cc = s*8 + lk*2;
        const u32* base = act + row*256;
        uint4 d0 = *(const uint4*)(base + (((cc    ) ^ (row & 7)) << 2));
        uint4 d1 = *(const uint4*)(base + (((cc + 1) ^ (row & 7)) << 2));
        u32 q[8] = {d0.x,d0.y,d0.z,d0.w,d1.x,d1.y,d1.z,d1.w};
        #pragma unroll
        for (int j = 0; j < 8; ++j) {
          ah[rt][j] = (short)(q[j] >> 16);
          al[rt][j] = (short)(q[j] & 0xffff);
        }
      }
      #pragma unroll
      for (int ct = 0; ct < 4; ++ct)
        #pragma unroll
        for (int rt = 0; rt < 4; ++rt) {
          acc[rt][ct] = __builtin_amdgcn_mfma_f32_16x16x32_bf16(ah[rt], bh[pb][ct],  acc[rt][ct], 0,0,0);
          acc[rt][ct] = __builtin_amdgcn_mfma_f32_16x16x32_bf16(al[rt], bh[pb][ct],  acc[rt][ct], 0,0,0);
          acc[rt][ct] = __builtin_amdgcn_mfma_f32_16x16x32_bf16(ah[rt], blo[pb][ct], acc[rt][ct], 0,0,0);
        }
    }
    const float* bptr = (lyr < nbs) ? (bs + lyr*256) : bl;
    const bool dorelu = (lyr < L-1) || (FIN == 1);
    #pragma unroll
    for (int ct = 0; ct < 4; ++ct) {
      float bv = bptr[cg*64 + ct*16 + lr];
      #pragma unroll
      for (int rt = 0; rt < 4; ++rt)
        #pragma unroll
        for (int g = 0; g < 4; ++g) {
          float xv = acc[rt][ct][g] + bv;
          acc[rt][ct][g] = dorelu ? fmaxf(xv, 0.f) : xv;
        }
    }
    if (lyr == L-1) break;
    __syncthreads();
    #pragma unroll
    for (int ct = 0; ct < 4; ++ct) {
      int n = cg*64 + ct*16 + lr;
      #pragma unroll
      for (int rt = 0; rt < 4; ++rt)
        #pragma unroll
        for (int g = 0; g < 4; ++g) {
          int row = wrow + rt*16 + lk*4 + g;
          act[row*256 + (((n >> 2) ^ (row & 7)) << 2) + (n & 3)] = packhl(acc[rt][ct][g]);
        }
    }
  }

  if (FIN == 0) {
    #pragma unroll
    for (int ct = 0; ct < 4; ++ct) {
      int n = cg*64 + ct*16 + lr;
      #pragma unroll
      for (int rt = 0; rt < 4; ++rt)
        #pragma unroll
        for (int g = 0; g < 4; ++g) {
          long m = m0 + wrow + rt*16 + lk*4 + g;
          Cout[m*256 + n] = acc[rt][ct][g];
        }
    }
  } else {
    float part[4][4];
    #pragma unroll
    for (int rt = 0; rt < 4; ++rt)
      #pragma unroll
      for (int g = 0; g < 4; ++g) part[rt][g] = 0.f;
    #pragma unroll
    for (int ct = 0; ct < 4; ++ct) {
      float vw = vWl[cg*64 + ct*16 + lr];
      #pragma unroll
      for (int rt = 0; rt < 4; ++rt)
        #pragma unroll
        for (int g = 0; g < 4; ++g) part[rt][g] += acc[rt][ct][g] * vw;
    }
    #pragma unroll
    for (int o = 1; o < 16; o <<= 1)
      #pragma unroll
      for (int rt = 0; rt < 4; ++rt)
        #pragma unroll
        for (int g = 0; g < 4; ++g) part[rt][g] += __shfl_xor(part[rt][g], o, 64);
    __syncthreads();
    float* ep = (float*)act;                      // [4][128]
    if ((l & 15) == 0) {
      #pragma unroll
      for (int rt = 0; rt < 4; ++rt)
        #pragma unroll
        for (int g = 0; g < 4; ++g)
          ep[cg*128 + wrow + rt*16 + lk*4 + g] = part[rt][g];
    }
    __syncthreads();
    for (int r = tid; r < 128; r += 512)
      eout[m0 + r] = ep[r] + ep[128 + r] + ep[256 + r] + ep[384 + r] + vbl[0];
  }
}

// ---------------------------------------------------------------------------
// Fused softmax + context over henc (t-major, packed hi/lo).
// e layout: e[t*CB + b].
// ---------------------------------------------------------------------------
__global__ __launch_bounds__(256,2) void k_attn(const float* __restrict__ e,
    const u32* __restrict__ henc, float* __restrict__ ct, int CB)
{
  __shared__ float as[512];
  __shared__ float red[8];
  const int b = blockIdx.x, tid = threadIdx.x;
  const int lane = tid & 63, w = tid >> 6;
  float v0 = e[(size_t)tid*CB + b];
  float v1 = e[(size_t)(tid + 256)*CB + b];
  float m = fmaxf(v0, v1);
  #pragma unroll
  for (int o = 32; o; o >>= 1) m = fmaxf(m, __shfl_xor(m, o, 64));
  if (!lane) red[w] = m;
  __syncthreads();
  m = fmaxf(fmaxf(red[0], red[1]), fmaxf(red[2], red[3]));
  float x0 = expf(v0 - m), x1 = expf(v1 - m);
  float sm = x0 + x1;
  #pragma unroll
  for (int o = 32; o; o >>= 1) sm += __shfl_xor(sm, o, 64);
  if (!lane) red[4 + w] = sm;
  __syncthreads();
  float inv = 1.f / (red[4] + red[5] + red[6] + red[7]);
  as[tid] = x0 * inv;
  as[256 + tid] = x1 * inv;
  __syncthreads();
  float acc = 0.f;
  const u32* ep = henc + (size_t)(CB + b)*256 + tid;   // slot 1, unit=tid
  const size_t ts = (size_t)CB * 256;
  #pragma unroll 8
  for (int t = 0; t < 512; ++t) acc += as[t] * unpackhl(ep[t*ts]);
  ct[b*H_ + tid] = acc;
}

__global__ __launch_bounds__(256,2) void k_dec_cell(
    const float* __restrict__ ct, float* __restrict__ s, const float* __restrict__ dWt,
    const float* __restrict__ bih, const float* __restrict__ bhh,
    float* __restrict__ dec, int step)
{
  __shared__ float xt[8][516];
  const int tid = threadIdx.x;
  const int b0 = blockIdx.x * 8;
  for (int f = tid; f < 8*128; f += 256) {
    int bb = f >> 7, k4 = f & 127;
    float4 v = (k4 < 64) ? *(const float4*)(ct + (b0+bb)*H_ + k4*4)
                         : *(const float4*)(s  + (b0+bb)*H_ + (k4-64)*4);
    *(float4*)(&xt[bb][k4*4]) = v;
  }
  __syncthreads();
  const int u = tid;
  float ai[8], ag[8], ao[8];
  #pragma unroll
  for (int bb = 0; bb < 8; ++bb) { ai[bb]=0.f; ag[bb]=0.f; ao[bb]=0.f; }
  #pragma unroll 2
  for (int k = 0; k < 512; ++k) {
    float wi = dWt[k*768 + u];
    float wg = dWt[k*768 + 256 + u];
    float wo = dWt[k*768 + 512 + u];
    #pragma unroll
    for (int bb = 0; bb < 8; ++bb) {
      float xv = xt[bb][k];
      ai[bb] += xv*wi; ag[bb] += xv*wg; ao[bb] += xv*wo;
    }
  }
  float bi = bih[u]       + bhh[u];
  float bg = bih[512 + u] + bhh[512 + u];
  float bo = bih[768 + u] + bhh[768 + u];
  #pragma unroll
  for (int bb = 0; bb < 8; ++bb) {
    int b = b0 + bb;
    float cn = sigm(ai[bb] + bi) * tanhf(ag[bb] + bg);
    float hn = sigm(ao[bb] + bo) * tanhf(cn);
    s[b*H_ + u] = hn;
    dec[((size_t)b*OL_ + step)*H_ + u] = hn;
  }
}

__global__ __launch_bounds__(256,2) void k_outproj(
    const float* __restrict__ dec, const float* __restrict__ oW,
    const float* __restrict__ ob, float* __restrict__ out)
{
  const int tid = threadIdx.x;
  const int m0 = blockIdx.x * 16;
  const int d = tid & 63, rr = tid >> 6;
  float bv = ob[d];
  for (int p = 0; p < 4; ++p) {
    int m = m0 + p*4 + rr;
    const float* ar = dec + (size_t)m*H_;
    float acc = bv;
    #pragma unroll 4
    for (int k = 0; k < H_; ++k) acc += ar[k] * oW[k*64 + d];
    out[(size_t)m*64 + d] = acc;
  }
}

// ---------------------------------------------------------------------------
extern "C" void kernel_launch(void* const* d_in, const int* in_sizes, int n_in,
                              void* d_out, int out_size, void* d_ws, size_t ws_size,
                              hipStream_t stream)
{
  (void)in_sizes; (void)n_in;
  const float* x    = (const float*)d_in[0];
  const float* inW  = (const float*)d_in[1];
  const float* inb  = (const float*)d_in[2];
  const float* eWih = (const float*)d_in[3];
  const float* eWhh = (const float*)d_in[4];
  const float* ebih = (const float*)d_in[5];
  const float* ebhh = (const float*)d_in[6];
  const float* dWih = (const float*)d_in[7];
  const float* dbih = (const float*)d_in[9];
  const float* dbhh = (const float*)d_in[10];
  const float* wWs  = (const float*)d_in[11];
  const float* wbs  = (const float*)d_in[12];
  const float* wWl  = (const float*)d_in[13];
  const float* wbl  = (const float*)d_in[14];
  const float* uWs  = (const float*)d_in[15];
  const float* ubs  = (const float*)d_in[16];
  const float* uWl  = (const float*)d_in[17];
  const float* ubl  = (const float*)d_in[18];
  const float* vWs  = (const float*)d_in[19];
  const float* vbs  = (const float*)d_in[20];
  const float* vWl  = (const float*)d_in[21];
  const float* vbl  = (const float*)d_in[22];
  const float* oW   = (const float*)d_in[23];
  const float* ob   = (const float*)d_in[24];
  float* out = (float*)d_out;

  hipFuncSetAttribute((const void*)k_mlp<0,0>, hipFuncAttributeMaxDynamicSharedMemorySize, 131072);
  hipFuncSetAttribute((const void*)k_mlp<1,1>, hipFuncAttributeMaxDynamicSharedMemorySize, 131072);
  hipFuncSetAttribute((const void*)k_mlp<2,0>, hipFuncAttributeMaxDynamicSharedMemorySize, 131072);

  const size_t avail = ws_size / 4;
  auto need = [](int cb) -> size_t {
    return (size_t)(T_+1)*cb*256        // henc (u32)
         + (size_t)cb*T_*256            // whs
         + (size_t)cb*3328               // sbuf,us,ctx,dec,e
         + 1300000ull;                   // preps + cnt + pad
  };
  int CB = 512;
  while (CB > 128 && need(CB) > avail) CB >>= 1;
  if (need(CB) > avail) { hipMemsetAsync(d_out, 0, (size_t)out_size*4, stream); return; }

  float* wsf = (float*)d_ws;
  size_t o = 0;
  u32* henc = (u32*)(wsf + o);  o += (size_t)(T_+1)*CB*256;
  float* whs = wsf + o;  o += (size_t)CB*T_*256;
  float* sbuf= wsf + o;  o += (size_t)CB*256;
  float* us  = wsf + o;  o += (size_t)CB*256;
  float* ctx = wsf + o;  o += (size_t)CB*256;
  float* dec = wsf + o;  o += (size_t)CB*2048;
  float* e   = wsf + o;  o += (size_t)CB*512;
  unsigned* cnt = (unsigned*)(wsf + o); o += 64;
  float* WpT = wsf + o;  o += 65536;
  float* bp  = wsf + o;  o += 1024;
  float* dWt = wsf + o;  o += 393216;
  u16* whhFL = (u16*)(wsf + o);  o += 262144;
  u16* wpFL  = (u16*)(wsf + o);  o += 65536;
  u16* mlpFL = (u16*)(wsf + o);

  // ---- weight preps (chunk-invariant)
  k_wpt<<<256, 256, 0, stream>>>(inW, eWih, WpT);
  k_bp <<<4,   256, 0, stream>>>(inb, eWih, ebih, ebhh, bp);
  k_dwt<<<1536,256, 0, stream>>>(dWih, dWt);
  k_whhfl<<<1024,256,0,stream>>>(eWhh, whhFL);
  k_wpfl <<<256, 256,0,stream>>>(WpT, wpFL);
  k_wall <<<dim3(256,15), 256, 0, stream>>>(wWs, wWl, uWs, uWl, vWs, mlpFL);

  const int gBig = CB * 4;
  const int gU   = CB / 128;
  const int cbm1 = CB - 1;

  for (int c0 = 0; c0 < B_; c0 += CB) {
    const float* xc = x + (size_t)c0*T_*DIN_;
    float* outc = out + (size_t)c0*OL_*DOUT_;

    hipMemsetAsync(henc, 0, (size_t)CB*1024, stream);     // slot 0 = h(-1) = 0
    hipMemsetAsync(cnt, 0, 256, stream);
    hipMemsetAsync(sbuf, 0, (size_t)CB*1024, stream);     // decode s0 = 0

    // ---- clustered persistent encoder (all T steps, one launch)
    k_enc<<<dim3(CB/16, 8), 256, 0, stream>>>(xc, whhFL, wpFL, bp, henc, cnt, CB);

    // ---- whs = w_mlp(enc)   rows m' = t*CB + b  (= henc slots 1..512 linear)
    k_mlp<2,0><<<gBig, 512, 131072, stream>>>((const float*)(henc + (size_t)CB*256),
                                              nullptr, mlpFL, wbs, wbl,
                                              whs, nullptr, nullptr, nullptr, 4, 3, 0);

    // ---- decode loop
    for (int step = 0; step < OL_; ++step) {
      k_mlp<0,0><<<gU, 512, 131072, stream>>>(sbuf, nullptr, mlpFL + 4ull*131072, ubs, ubl,
                                              us, nullptr, nullptr, nullptr, 4, 3, 0);
      k_mlp<1,1><<<gBig, 512, 131072, stream>>>(whs, us, mlpFL + 8ull*131072, vbs, nullptr,
                                                nullptr, e, vWl, vbl, 7, 7, cbm1);
      k_attn<<<CB, 256, 0, stream>>>(e, henc, ctx, CB);
      k_dec_cell<<<CB/8, 256, 0, stream>>>(ctx, sbuf, dWt, dbih, dbhh, dec, step);
    }
    k_outproj<<<CB/2, 256, 0, stream>>>(dec, oW, ob, outc);
  }
}